// Round 3
// baseline (5530.921 us; speedup 1.0000x reference)
//
#include <hip/hip_runtime.h>

#define DEV __device__ __forceinline__

typedef _Float16 f16;
typedef _Float16 f16x8 __attribute__((ext_vector_type(8)));
typedef _Float16 f16x4 __attribute__((ext_vector_type(4)));
typedef _Float16 f16x2 __attribute__((ext_vector_type(2)));
typedef float f32x4 __attribute__((ext_vector_type(4)));

DEV float sigmoidf_(float x) { return 1.0f / (1.0f + __expf(-x)); }
DEV float tanhf2_(float x)   { return 1.0f - 2.0f / (__expf(2.0f * x) + 1.0f); }

// async global->LDS, 16B per lane (used by gemm16 only)
DEV void load_lds16(const void* g, void* l) {
    __builtin_amdgcn_global_load_lds(
        (const __attribute__((address_space(1))) char*)(const char*)g,
        (__attribute__((address_space(3))) char*)(unsigned int)(unsigned long long)(char*)l,
        16, 0, 0);
}

// ---------------------------------------------------------------------------
// LSTM weight prep for persistent kernel. GEMM N-position n in [0,1024):
//   nc = n>>8, p = n&255, wc = p>>6, q = p&63, gate g = q>>4, ci = q&15
//   unit u = nc*64 + wc*16 + ci ; src row = g*256 + u   (torch order i,f,g,o)
// W0 dst [1024][288]: cols 0..15 = w_ih (K=16), 16..271 = w_hh, 272..287 = 0
// W1 dst [1024][512]: cols 0..255 = w_ih, 256..511 = w_hh
// ---------------------------------------------------------------------------
__global__ void prep_w0_kernel(const float* __restrict__ wih,
                               const float* __restrict__ whh,
                               f16* __restrict__ dst) {
    int idx = blockIdx.x * 256 + threadIdx.x;
    if (idx >= 1024 * 288) return;
    int rd = idx / 288, k = idx - rd * 288;
    int nc = rd >> 8, p = rd & 255, wc = p >> 6, q = p & 63;
    int g = q >> 4, ci = q & 15;
    int u = nc * 64 + wc * 16 + ci;
    int src = g * 256 + u;
    float v;
    if (k < 16)        v = wih[src * 16 + k];
    else if (k < 272)  v = whh[src * 256 + (k - 16)];
    else               v = 0.f;
    dst[idx] = (f16)v;
}

__global__ void prep_w1_kernel(const float* __restrict__ wih,
                               const float* __restrict__ whh,
                               f16* __restrict__ dst) {
    int idx = blockIdx.x * 256 + threadIdx.x;
    if (idx >= 1024 * 512) return;
    int rd = idx >> 9, k = idx & 511;
    int nc = rd >> 8, p = rd & 255, wc = p >> 6, q = p & 63;
    int g = q >> 4, ci = q & 15;
    int u = nc * 64 + wc * 16 + ci;
    int src = g * 256 + u;
    float v = (k < 256) ? wih[src * 256 + k] : whh[src * 256 + (k - 256)];
    dst[idx] = (f16)v;
}

__global__ void prep_bias4_kernel(const float* __restrict__ bi,
                                  const float* __restrict__ bh,
                                  float* __restrict__ dst) {  // [u*4+g]
    int idx = blockIdx.x * 256 + threadIdx.x;
    if (idx >= 1024) return;
    int u = idx >> 2, g = idx & 3;
    dst[idx] = bi[g * 256 + u] + bh[g * 256 + u];
}

// generic [K,N] fp32 -> [N,K] fp16 transpose
__global__ void prep_wt_kernel(const float* __restrict__ src, f16* __restrict__ dst,
                               int K, int N) {
    int idx = blockIdx.x * 256 + threadIdx.x;
    if (idx >= K * N) return;
    int n = idx / K, k = idx - n * K;
    dst[idx] = (f16)src[(size_t)k * N + n];
}

// ---------------------------------------------------------------------------
// Persistent LSTM: one block owns 48 node-rows for all 60 steps.
// c-state in VGPRs, h-state in LDS, weights streamed from L2 direct to
// B-fragments (each wave owns a private 64-col slice -> no k-loop barriers).
// ---------------------------------------------------------------------------
#define ROWS 48
#define LDA0 296   // 288 + 8 pad (f16 elems)
#define LDA1 520   // 512 + 8
#define LDHS 264   // 256 + 8
#define K0c  288
#define K1c  512

template<int KC, int LDA>
DEV void gemm_nc(const f16* __restrict__ sAbuf, const f16* __restrict__ Bbase, int K,
                 f32x4 acc[3][4], int l15, int l4)
{
    f16x8 bn[4];
#pragma unroll
    for (int j = 0; j < 4; ++j)
        bn[j] = *(const f16x8*)(Bbase + (size_t)j * 16 * K);
#pragma unroll
    for (int kc = 0; kc < KC; ++kc) {
        f16x8 bc[4];
#pragma unroll
        for (int j = 0; j < 4; ++j) bc[j] = bn[j];
        if (kc + 1 < KC) {
#pragma unroll
            for (int j = 0; j < 4; ++j)
                bn[j] = *(const f16x8*)(Bbase + (size_t)j * 16 * K + (kc + 1) * 32);
        }
        f16x8 a[3];
#pragma unroll
        for (int i = 0; i < 3; ++i)
            a[i] = *(const f16x8*)&sAbuf[(i * 16 + l15) * LDA + kc * 32 + l4 * 8];
#pragma unroll
        for (int i = 0; i < 3; ++i)
#pragma unroll
            for (int j = 0; j < 4; ++j)
                acc[i][j] = __builtin_amdgcn_mfma_f32_16x16x32_f16(a[i], bc[j], acc[i][j], 0, 0, 0);
    }
}

DEV void cell_update(f32x4 acc[3][4], float cr[3][4], const float4 bb,
                     f16* __restrict__ hdst, int ldh, int u, int l4)
{
#pragma unroll
    for (int i = 0; i < 3; ++i)
#pragma unroll
        for (int r = 0; r < 4; ++r) {
            int row = i * 16 + l4 * 4 + r;
            float gi = sigmoidf_(acc[i][0][r] + bb.x);
            float gf = sigmoidf_(acc[i][1][r] + bb.y);
            float gg = tanhf2_(acc[i][2][r] + bb.z);
            float go = sigmoidf_(acc[i][3][r] + bb.w);
            float cn = gf * cr[i][r] + gi * gg;
            cr[i][r] = cn;
            hdst[row * ldh + u] = (f16)(go * tanhf2_(cn));
        }
}

__global__ __launch_bounds__(256, 1) void lstm_persistent_kernel(
    const float* __restrict__ x_seq,
    const f16* __restrict__ W0, const f16* __restrict__ W1,
    const float* __restrict__ b40, const float* __restrict__ b41,
    f16* __restrict__ node_out, int ldno, int M)
{
    extern __shared__ __align__(16) f16 smem[];
    f16* sA0 = smem;                          // [48][LDA0]
    f16* sA1 = smem + ROWS * LDA0;            // [48][LDA1]
    f16* sHs = sA1 + ROWS * LDA1;             // [48][LDHS]

    const int tid = threadIdx.x;
    const int wc = tid >> 6, lane = tid & 63;
    const int l15 = lane & 15, l4 = lane >> 4;
    const int rowbase = blockIdx.x * ROWS;

    // init: zero A0/A1 (h0=h1=0, zero pad cols), load x_0
    for (int i = tid; i < ROWS * LDA0; i += 256) sA0[i] = (f16)0.f;
    for (int i = tid; i < ROWS * LDA1; i += 256) sA1[i] = (f16)0.f;
    __syncthreads();
    if (tid < 192) {
        int row = tid >> 2, cc = (tid & 3) * 4;
        int m = rowbase + row;
        f16x4 xv4 = {};
        if (m < M) {
            float4 xv = *(const float4*)(x_seq + (size_t)m * 960 + cc);
            xv4.x = (f16)xv.x; xv4.y = (f16)xv.y; xv4.z = (f16)xv.z; xv4.w = (f16)xv.w;
        }
        *(f16x4*)&sA0[row * LDA0 + cc] = xv4;
    }
    __syncthreads();

    float c0r[4][3][4] = {};
    float c1r[4][3][4] = {};

    for (int t = 0; t < 60; ++t) {
        // ---- layer 0: gates = [x_t|h0] @ W0^T, h0_t -> sA1 cols 0..255 ----
#pragma unroll
        for (int nc = 0; nc < 4; ++nc) {
            f32x4 acc[3][4] = {};
            const f16* Bb = W0 + (size_t)(nc * 256 + wc * 64 + l15) * K0c + l4 * 8;
            gemm_nc<9, LDA0>(sA0, Bb, K0c, acc, l15, l4);
            int u = nc * 64 + wc * 16 + l15;
            float4 bb = *(const float4*)&b40[u * 4];
            cell_update(acc, c0r[nc], bb, sA1, LDA1, u, l4);
        }
        __syncthreads();
        // ---- layer 1: gates = [h0_t|h1_{t-1}] @ W1^T, h1_t -> sHs ----
#pragma unroll
        for (int nc = 0; nc < 4; ++nc) {
            f32x4 acc[3][4] = {};
            const f16* Bb = W1 + (size_t)(nc * 256 + wc * 64 + l15) * K1c + l4 * 8;
            gemm_nc<16, LDA1>(sA1, Bb, K1c, acc, l15, l4);
            int u = nc * 64 + wc * 16 + l15;
            float4 bb = *(const float4*)&b41[u * 4];
            cell_update(acc, c1r[nc], bb, sHs, LDHS, u, l4);
        }
        __syncthreads();
        if (t < 59) {
            // h0_t: sA1[0..255] -> sA0[16..271]; h1_t: sHs -> sA1[256..511]
            for (int idx = tid; idx < 1536; idx += 256) {
                int row = idx >> 5, c8 = (idx & 31) * 8;
                *(f16x8*)&sA0[row * LDA0 + 16 + c8] = *(const f16x8*)&sA1[row * LDA1 + c8];
                *(f16x8*)&sA1[row * LDA1 + 256 + c8] = *(const f16x8*)&sHs[row * LDHS + c8];
            }
            // x_{t+1} -> sA0 cols 0..15
            if (tid < 192) {
                int row = tid >> 2, cc = (tid & 3) * 4;
                int m = rowbase + row;
                f16x4 xv4 = {};
                if (m < M) {
                    float4 xv = *(const float4*)(x_seq + (size_t)m * 960 + (t + 1) * 16 + cc);
                    xv4.x = (f16)xv.x; xv4.y = (f16)xv.y; xv4.z = (f16)xv.z; xv4.w = (f16)xv.w;
                }
                *(f16x4*)&sA0[row * LDA0 + cc] = xv4;
            }
            __syncthreads();
        }
    }

    // write h1_59 (node embedding) to global
    for (int idx = tid; idx < 1536; idx += 256) {
        int row = idx >> 5, c8 = (idx & 31) * 8;
        int m = rowbase + row;
        if (m < M)
            *(f16x8*)&node_out[(size_t)m * ldno + c8] = *(const f16x8*)&sHs[row * LDHS + c8];
    }
}

// ---------------------------------------------------------------------------
// Generic f16 MFMA GEMM: C = act(A[M,lda(K cols)] @ Bt[N,K]^T + bias)
// ---------------------------------------------------------------------------
__global__ __launch_bounds__(256) void gemm16_kernel(
    const f16* __restrict__ A, int lda,
    const f16* __restrict__ Bt, int K,
    const float* __restrict__ bias,
    f16* __restrict__ C16, float* __restrict__ C32, int ldc,
    int act, int M)
{
    __shared__ __align__(16) f16 sA[128 * 32];
    __shared__ __align__(16) f16 sB[128 * 32];
    const int tid = threadIdx.x;
    const int w = tid >> 6, lane = tid & 63;
    const int m0 = blockIdx.x * 128, n0 = blockIdx.y * 128;
    const int arow = lane >> 2, achk = (lane & 3) * 8;
    const int frow = lane & 15, fchk = (lane >> 4) * 8;
    const int wr = (w >> 1) * 64, wcn = (w & 1) * 64;

    f32x4 acc[4][4] = {};

    for (int k0 = 0; k0 < K; k0 += 32) {
        __syncthreads();
#pragma unroll
        for (int c = 0; c < 2; ++c) {
            int R = c * 64 + w * 16;
            load_lds16(A + (size_t)(m0 + R + arow) * lda + k0 + achk, sA + R * 32);
            load_lds16(Bt + (size_t)(n0 + R + arow) * K + k0 + achk, sB + R * 32);
        }
        __syncthreads();
        f16x8 af[4], bf[4];
#pragma unroll
        for (int i = 0; i < 4; ++i)
            af[i] = *(const f16x8*)&sA[(wr + i * 16 + frow) * 32 + fchk];
#pragma unroll
        for (int j = 0; j < 4; ++j)
            bf[j] = *(const f16x8*)&sB[(wcn + j * 16 + frow) * 32 + fchk];
#pragma unroll
        for (int i = 0; i < 4; ++i)
#pragma unroll
            for (int j = 0; j < 4; ++j)
                acc[i][j] = __builtin_amdgcn_mfma_f32_16x16x32_f16(af[i], bf[j], acc[i][j], 0, 0, 0);
    }

    const int rbase = m0 + wr + (lane >> 4) * 4;
#pragma unroll
    for (int i = 0; i < 4; ++i) {
#pragma unroll
        for (int r = 0; r < 4; ++r) {
            int m = rbase + i * 16 + r;
            if (m >= M) continue;
#pragma unroll
            for (int j = 0; j < 4; ++j) {
                int n = n0 + wcn + j * 16 + (lane & 15);
                float v = acc[i][j][r] + bias[n];
                if (act == 1) v = fmaxf(v, 0.f);
                if (C16) C16[(size_t)m * ldc + n] = (f16)v;
                else     C32[(size_t)m * ldc + n] = v;
            }
        }
    }
}

// ---------------------------------------------------------------------------
// Edge preprocessing
// ---------------------------------------------------------------------------
__global__ void mean_sum_kernel(const float* __restrict__ a, int n, float* __restrict__ out) {
    __shared__ float s[256];
    float loc = 0.f;
    for (int i = blockIdx.x * 256 + threadIdx.x; i < n; i += gridDim.x * 256) loc += a[i];
    s[threadIdx.x] = loc;
    __syncthreads();
    for (int off = 128; off; off >>= 1) {
        if (threadIdx.x < off) s[threadIdx.x] += s[threadIdx.x + off];
        __syncthreads();
    }
    if (threadIdx.x == 0) atomicAdd(out, s[0]);
}

__global__ void hist_kernel(const int* __restrict__ ei, int Ne, int Nn,
                            int* __restrict__ counts) {
    int e = blockIdx.x * 256 + threadIdx.x;
    if (e >= Ne + Nn) return;
    int d = (e < Ne) ? ei[Ne + e] : (e - Ne);
    atomicAdd(&counts[d], 1);
}

__global__ void scan_kernel(const int* __restrict__ counts, int* __restrict__ offsets, int n) {
    __shared__ int s[256];
    int tid = threadIdx.x;
    int chunk = (n + 255) / 256;
    int b = tid * chunk;
    int loc = 0;
    for (int j = 0; j < chunk; ++j) { int i = b + j; if (i < n) loc += counts[i]; }
    s[tid] = loc;
    __syncthreads();
    for (int off = 1; off < 256; off <<= 1) {
        int v = (tid >= off) ? s[tid - off] : 0;
        __syncthreads();
        s[tid] += v;
        __syncthreads();
    }
    int run = (tid == 0) ? 0 : s[tid - 1];
    for (int j = 0; j < chunk; ++j) {
        int i = b + j;
        if (i < n) { offsets[i] = run; run += counts[i]; }
    }
    if (tid == 255) offsets[n] = run;
}

__global__ void scatter_kernel(const int* __restrict__ ei, const float* __restrict__ ea,
                               const float* __restrict__ sump, float inv_ne, int Ne, int Nn,
                               int* __restrict__ cursor, int* __restrict__ src_sorted,
                               float* __restrict__ ea_sorted) {
    int e = blockIdx.x * 256 + threadIdx.x;
    if (e >= Ne + Nn) return;
    int s, d; float a;
    if (e < Ne) { s = ei[e]; d = ei[Ne + e]; a = ea[e]; }
    else        { s = e - Ne; d = s; a = sump[0] * inv_ne; }
    int pos = atomicAdd(&cursor[d], 1);
    src_sorted[pos] = s;
    ea_sorted[pos] = a;
}

// ---------------------------------------------------------------------------
// GATv2 attention + aggregation (fp16 xl/xr), one block per dst node.
// ---------------------------------------------------------------------------
__global__ __launch_bounds__(256) void gat_aggregate_kernel(
    const f16* __restrict__ xl, const f16* __restrict__ xr,
    const float* __restrict__ we, const float* __restrict__ att,
    const float* __restrict__ bias,
    const int* __restrict__ offsets, const int* __restrict__ src_sorted,
    const float* __restrict__ ea_sorted,
    float* __restrict__ logit_buf, f16* __restrict__ out, int ldo, int N)
{
    __shared__ float s_xr[512], s_we[512], s_att[512];
    __shared__ float s_wmax[32], s_mx[8], s_den[8], s_rden[8];
    __shared__ float s_alpha[256];
    __shared__ int s_src[32];
    const int i = blockIdx.x;
    const int tid = threadIdx.x;
    s_xr[tid]       = (float)xr[(size_t)i * 512 + tid];
    s_xr[tid + 256] = (float)xr[(size_t)i * 512 + tid + 256];
    s_we[tid] = we[tid]; s_we[tid + 256] = we[tid + 256];
    s_att[tid] = att[tid]; s_att[tid + 256] = att[tid + 256];
    if (tid < 8) s_den[tid] = 0.f;
    __syncthreads();

    const int beg = offsets[i], end = offsets[i + 1];
    const int w = tid >> 6, lane = tid & 63;

    float wm[4] = {-1e30f, -1e30f, -1e30f, -1e30f};
    for (int e = beg + w; e < end; e += 4) {
        int s = src_sorted[e];
        float a = ea_sorted[e];
        float part[4];
#pragma unroll
        for (int cc = 0; cc < 4; ++cc) {
            int col = cc * 128 + lane * 2;
            f16x2 xv = *(const f16x2*)&xl[(size_t)s * 512 + col];
            float v0 = (float)xv.x + s_xr[col]     + a * s_we[col];
            float v1 = (float)xv.y + s_xr[col + 1] + a * s_we[col + 1];
            v0 = (v0 > 0.f) ? v0 : 0.2f * v0;
            v1 = (v1 > 0.f) ? v1 : 0.2f * v1;
            part[cc] = v0 * s_att[col] + v1 * s_att[col + 1];
        }
#pragma unroll
        for (int off = 16; off; off >>= 1)
#pragma unroll
            for (int cc = 0; cc < 4; ++cc) part[cc] += __shfl_xor(part[cc], off);
        if ((lane & 31) == 0) {
            int hb = lane >> 5;
#pragma unroll
            for (int cc = 0; cc < 4; ++cc) {
                logit_buf[(size_t)e * 8 + 2 * cc + hb] = part[cc];
                wm[cc] = fmaxf(wm[cc], part[cc]);
            }
        }
    }
    if ((lane & 31) == 0) {
        int hb = lane >> 5;
#pragma unroll
        for (int cc = 0; cc < 4; ++cc) s_wmax[w * 8 + 2 * cc + hb] = wm[cc];
    }
    __syncthreads();
    if (tid < 8) {
        float m = fmaxf(fmaxf(s_wmax[tid], s_wmax[8 + tid]),
                        fmaxf(s_wmax[16 + tid], s_wmax[24 + tid]));
        s_mx[tid] = m;
    }
    __syncthreads();

    for (int e = beg + tid; e < end; e += 256) {
#pragma unroll
        for (int h = 0; h < 8; ++h) {
            float ex = __expf(logit_buf[(size_t)e * 8 + h] - s_mx[h]);
            logit_buf[(size_t)e * 8 + h] = ex;
            atomicAdd(&s_den[h], ex);
        }
    }
    __syncthreads();
    if (tid < 8) s_rden[tid] = 1.f / s_den[tid];
    __syncthreads();

    float acc0 = 0.f, acc1 = 0.f;
    const int c2 = tid * 2, hh = tid >> 5;
    for (int chunk = beg; chunk < end; chunk += 32) {
        int cnt = min(32, end - chunk);
        if (tid < cnt) s_src[tid] = src_sorted[chunk + tid];
        int eo = tid >> 3, hq = tid & 7;
        if (eo < cnt) s_alpha[tid] = logit_buf[(size_t)(chunk + eo) * 8 + hq] * s_rden[hq];
        __syncthreads();
        for (int j = 0; j < cnt; ++j) {
            int s = s_src[j];
            f16x2 xv = *(const f16x2*)&xl[(size_t)s * 512 + c2];
            float al = s_alpha[j * 8 + hh];
            acc0 += al * (float)xv.x;
            acc1 += al * (float)xv.y;
        }
        __syncthreads();
    }
    float v0 = acc0 + bias[c2];
    float v1 = acc1 + bias[c2 + 1];
    v0 = (v0 > 0.f) ? v0 : __expf(v0) - 1.f;
    v1 = (v1 > 0.f) ? v1 : __expf(v1) - 1.f;
    f16x2 ov; ov.x = (f16)v0; ov.y = (f16)v1;
    *(f16x2*)&out[(size_t)i * ldo + c2] = ov;
}

// fc2: out[n] = H[n,:512] . w + b (fp32)
__global__ void fc2_kernel(const float* __restrict__ H, const float* __restrict__ w,
                           const float* __restrict__ b, float* __restrict__ out, int N) {
    int wv = threadIdx.x >> 6, lane = threadIdx.x & 63;
    int node = blockIdx.x * 4 + wv;
    if (node >= N) return;
    float s = 0.f;
#pragma unroll
    for (int j = 0; j < 8; ++j)
        s += H[(size_t)node * 512 + j * 64 + lane] * w[j * 64 + lane];
#pragma unroll
    for (int off = 32; off; off >>= 1) s += __shfl_xor(s, off, 64);
    if (lane == 0) out[node] = s + b[0];
}

// ---------------------------------------------------------------------------
extern "C" void kernel_launch(void* const* d_in, const int* in_sizes, int n_in,
                              void* d_out, int out_size, void* d_ws, size_t ws_size,
                              hipStream_t stream) {
    const float* x_seq     = (const float*)d_in[0];
    const int*   edge_index= (const int*)d_in[1];
    const float* edge_attr = (const float*)d_in[2];
    const float* w_ih0 = (const float*)d_in[3];
    const float* w_hh0 = (const float*)d_in[4];
    const float* b_ih0 = (const float*)d_in[5];
    const float* b_hh0 = (const float*)d_in[6];
    const float* w_ih1 = (const float*)d_in[7];
    const float* w_hh1 = (const float*)d_in[8];
    const float* b_ih1 = (const float*)d_in[9];
    const float* b_hh1 = (const float*)d_in[10];
    const float* g0_wl = (const float*)d_in[11];
    const float* g0_bl = (const float*)d_in[12];
    const float* g0_wr = (const float*)d_in[13];
    const float* g0_br = (const float*)d_in[14];
    const float* g0_we = (const float*)d_in[15];
    const float* g0_att= (const float*)d_in[16];
    const float* g0_bias=(const float*)d_in[17];
    const float* g1_wl = (const float*)d_in[18];
    const float* g1_bl = (const float*)d_in[19];
    const float* g1_wr = (const float*)d_in[20];
    const float* g1_br = (const float*)d_in[21];
    const float* g1_we = (const float*)d_in[22];
    const float* g1_att= (const float*)d_in[23];
    const float* g1_bias=(const float*)d_in[24];
    const float* fc1_w = (const float*)d_in[25];
    const float* fc1_b = (const float*)d_in[26];
    const float* fc2_w = (const float*)d_in[27];
    const float* fc2_b = (const float*)d_in[28];
    float* out = (float*)d_out;

    const int Nn = in_sizes[0] / (60 * 16);   // 10000
    const int Ne = in_sizes[1] / 2;           // 320000
    const int Etot = Ne + Nn;
    const int MT = (Nn + 127) / 128;          // 79
    const int Mpad = MT * 128;                // 10112
    const int NB = (Nn + ROWS - 1) / ROWS;    // 209

    size_t off = 0;
    auto alloc = [&](size_t bytes) -> void* {
        void* r = (char*)d_ws + off;
        off += (bytes + 255) & ~(size_t)255;
        return r;
    };
    f16* W0t   = (f16*)alloc((size_t)1024 * 288 * 2);
    f16* W1t   = (f16*)alloc((size_t)1024 * 512 * 2);
    float* b40 = (float*)alloc(1024 * 4);
    float* b41 = (float*)alloc(1024 * 4);
    f16* Wg0l  = (f16*)alloc((size_t)512 * 256 * 2);
    f16* Wg0r  = (f16*)alloc((size_t)512 * 256 * 2);
    f16* Wg1l  = (f16*)alloc((size_t)512 * 512 * 2);
    f16* Wg1r  = (f16*)alloc((size_t)512 * 512 * 2);
    f16* Wfc1  = (f16*)alloc((size_t)512 * 768 * 2);
    f16* fused = (f16*)alloc((size_t)Mpad * 768 * 2);
    f16* xlbuf = (f16*)alloc((size_t)Mpad * 512 * 2);
    f16* xrbuf = (f16*)alloc((size_t)Mpad * 512 * 2);
    f16* gbuf  = (f16*)alloc((size_t)Mpad * 512 * 2);
    float* hfc1= (float*)alloc((size_t)Mpad * 512 * 4);
    float* logit_buf = (float*)alloc((size_t)Etot * 8 * 4);
    int* counts  = (int*)alloc((size_t)Nn * 4);
    int* offsets = (int*)alloc((size_t)(Nn + 1) * 4);
    int* cursor  = (int*)alloc((size_t)Nn * 4);
    int* src_sorted = (int*)alloc((size_t)Etot * 4);
    float* ea_sorted = (float*)alloc((size_t)Etot * 4);
    float* meanp = (float*)alloc(256);

    // ---- weight prep ----
    prep_w0_kernel<<<dim3((1024 * 288 + 255) / 256), 256, 0, stream>>>(w_ih0, w_hh0, W0t);
    prep_w1_kernel<<<dim3((1024 * 512 + 255) / 256), 256, 0, stream>>>(w_ih1, w_hh1, W1t);
    prep_bias4_kernel<<<dim3(4), 256, 0, stream>>>(b_ih0, b_hh0, b40);
    prep_bias4_kernel<<<dim3(4), 256, 0, stream>>>(b_ih1, b_hh1, b41);
    prep_wt_kernel<<<dim3((256 * 512 + 255) / 256), 256, 0, stream>>>(g0_wl, Wg0l, 256, 512);
    prep_wt_kernel<<<dim3((256 * 512 + 255) / 256), 256, 0, stream>>>(g0_wr, Wg0r, 256, 512);
    prep_wt_kernel<<<dim3((512 * 512 + 255) / 256), 256, 0, stream>>>(g1_wl, Wg1l, 512, 512);
    prep_wt_kernel<<<dim3((512 * 512 + 255) / 256), 256, 0, stream>>>(g1_wr, Wg1r, 512, 512);
    prep_wt_kernel<<<dim3((768 * 512 + 255) / 256), 256, 0, stream>>>(fc1_w, Wfc1, 768, 512);

    // ---- edge prep (CSR by dst) ----
    hipMemsetAsync(meanp, 0, 4, stream);
    hipMemsetAsync(counts, 0, (size_t)Nn * 4, stream);
    mean_sum_kernel<<<dim3(256), 256, 0, stream>>>(edge_attr, Ne, meanp);
    hist_kernel<<<dim3((Etot + 255) / 256), 256, 0, stream>>>(edge_index, Ne, Nn, counts);
    scan_kernel<<<dim3(1), 256, 0, stream>>>(counts, offsets, Nn);
    hipMemcpyAsync(cursor, offsets, (size_t)Nn * 4, hipMemcpyDeviceToDevice, stream);
    scatter_kernel<<<dim3((Etot + 255) / 256), 256, 0, stream>>>(
        edge_index, edge_attr, meanp, 1.0f / (float)Ne, Ne, Nn, cursor, src_sorted, ea_sorted);

    // ---- persistent 2-layer LSTM, all 60 steps in one launch ----
    const int lds_bytes = (ROWS * LDA0 + ROWS * LDA1 + ROWS * LDHS) * 2;  // 103680
    static bool attr_set = false;
    if (!attr_set) {
        hipFuncSetAttribute((const void*)lstm_persistent_kernel,
                            hipFuncAttributeMaxDynamicSharedMemorySize, lds_bytes);
        attr_set = true;
    }
    lstm_persistent_kernel<<<dim3(NB), 256, lds_bytes, stream>>>(
        x_seq, W0t, W1t, b40, b41, fused, 768, Nn);
    // node embedding now in fused[:, 0:256] (lda 768)

    // ---- GAT layer 1 ----
    dim3 ggrid(MT, 4);
    gemm16_kernel<<<ggrid, 256, 0, stream>>>(fused, 768, Wg0l, 256, g0_bl, xlbuf, nullptr, 512, 0, Nn);
    gemm16_kernel<<<ggrid, 256, 0, stream>>>(fused, 768, Wg0r, 256, g0_br, xrbuf, nullptr, 512, 0, Nn);
    gat_aggregate_kernel<<<dim3(Nn), 256, 0, stream>>>(
        xlbuf, xrbuf, g0_we, g0_att, g0_bias, offsets, src_sorted, ea_sorted,
        logit_buf, gbuf, 512, Nn);

    // ---- GAT layer 2 (output straight into fused cols 256..767) ----
    gemm16_kernel<<<ggrid, 256, 0, stream>>>(gbuf, 512, Wg1l, 512, g1_bl, xlbuf, nullptr, 512, 0, Nn);
    gemm16_kernel<<<ggrid, 256, 0, stream>>>(gbuf, 512, Wg1r, 512, g1_br, xrbuf, nullptr, 512, 0, Nn);
    gat_aggregate_kernel<<<dim3(Nn), 256, 0, stream>>>(
        xlbuf, xrbuf, g1_we, g1_att, g1_bias, offsets, src_sorted, ea_sorted,
        logit_buf, fused + 256, 768, Nn);

    // ---- fusion MLP ----
    gemm16_kernel<<<ggrid, 256, 0, stream>>>(fused, 768, Wfc1, 768, fc1_b, nullptr, hfc1, 512, 1, Nn);
    fc2_kernel<<<dim3((Nn + 3) / 4), 256, 0, stream>>>(hfc1, fc2_w, fc2_b, out, Nn);
}

// Round 4
// 3909.330 us; speedup vs baseline: 1.4148x; 1.4148x over previous
//
#include <hip/hip_runtime.h>

#define DEV __device__ __forceinline__

typedef _Float16 f16;
typedef _Float16 f16x8 __attribute__((ext_vector_type(8)));
typedef _Float16 f16x2 __attribute__((ext_vector_type(2)));
typedef float f32x4 __attribute__((ext_vector_type(4)));

DEV float sigmoidf_(float x) { return 1.0f / (1.0f + __expf(-x)); }
DEV float tanhf2_(float x)   { return 1.0f - 2.0f / (__expf(2.0f * x) + 1.0f); }

// async global->LDS, 16B per lane. LDS dest = wave-uniform base + lane*16.
DEV void load_lds16(const void* g, void* l) {
    __builtin_amdgcn_global_load_lds(
        (const __attribute__((address_space(1))) char*)(const char*)g,
        (__attribute__((address_space(3))) char*)(unsigned int)(unsigned long long)(char*)l,
        16, 0, 0);
}

// ---------------------------------------------------------------------------
// LSTM weight prep: Wt[1024][K] fp16, column-order chosen so that in the MFMA
// C-layout the 4 gates of a unit land in one lane's 4 j-fragments.
// dst row rd: T=rd>>7, p=rd&127, wh=(p>>6)&1, j=(p>>4)&3, c=p&15
//   unit u = T*32 + wh*16 + c ; gate g = j ; src row = g*256+u
// ---------------------------------------------------------------------------
__global__ void prep_w0_kernel(const float* __restrict__ wih,
                               const float* __restrict__ whh,
                               f16* __restrict__ dst) {   // [1024,288]
    int idx = blockIdx.x * 256 + threadIdx.x;
    if (idx >= 1024 * 288) return;
    int rd = idx / 288, k = idx - rd * 288;
    int T = rd >> 7, p = rd & 127;
    int u = T * 32 + ((p >> 6) & 1) * 16 + (p & 15);
    int g = (p >> 4) & 3;
    int src = g * 256 + u;
    float v;
    if (k < 16)        v = wih[src * 16 + k];
    else if (k < 272)  v = whh[src * 256 + (k - 16)];
    else               v = 0.f;
    dst[idx] = (f16)v;
}

__global__ void prep_w1_kernel(const float* __restrict__ wih,
                               const float* __restrict__ whh,
                               f16* __restrict__ dst) {   // [1024,512]
    int idx = blockIdx.x * 256 + threadIdx.x;
    if (idx >= 1024 * 512) return;
    int rd = idx >> 9, k = idx & 511;
    int T = rd >> 7, p = rd & 127;
    int u = T * 32 + ((p >> 6) & 1) * 16 + (p & 15);
    int g = (p >> 4) & 3;
    int src = g * 256 + u;
    float v = (k < 256) ? wih[src * 256 + k] : whh[src * 256 + (k - 256)];
    dst[idx] = (f16)v;
}

__global__ void prep_bias4_kernel(const float* __restrict__ bi,
                                  const float* __restrict__ bh,
                                  float* __restrict__ dst) {  // [1024] = [u*4+g]
    int idx = blockIdx.x * 256 + threadIdx.x;
    if (idx >= 1024) return;
    int u = idx >> 2, g = idx & 3;
    dst[idx] = bi[g * 256 + u] + bh[g * 256 + u];
}

// generic [K,N] fp32 -> [N,K] fp16 transpose
__global__ void prep_wt_kernel(const float* __restrict__ src, f16* __restrict__ dst,
                               int K, int N) {
    int idx = blockIdx.x * 256 + threadIdx.x;
    if (idx >= K * N) return;
    int n = idx / K, k = idx - n * K;
    dst[idx] = (f16)src[(size_t)k * N + n];
}

// x_seq[:,0,:16] -> A0buf0 cols 0..15
__global__ void prep_x0_kernel(const float* __restrict__ x_seq, f16* __restrict__ A0,
                               int Nn) {
    int idx = blockIdx.x * 256 + threadIdx.x;
    if (idx >= Nn * 16) return;
    int m = idx >> 4, f = idx & 15;
    A0[(size_t)m * 288 + f] = (f16)x_seq[(size_t)m * 960 + f];
}

// ---------------------------------------------------------------------------
// LSTM step core (f16 MFMA): gates = A @ Wt^T (+bias), cell update.
// A [Mpad,lda] fp16, Wt [1024,K] fp16, K%32==0. Tile 128x128, 4 waves 2x2.
// ---------------------------------------------------------------------------
DEV void lstm_step_core(
    f16* __restrict__ sA, f16* __restrict__ sB,
    const f16* __restrict__ A, int lda, int K,
    const f16* __restrict__ Wt,
    const float* __restrict__ bias4,
    float* __restrict__ c_state,
    f16* __restrict__ hA, int ldhA, int offhA,
    f16* __restrict__ hB, int ldhB, int offhB,
    const float* __restrict__ xsrc, int tnext,
    int M)
{
    const int tid = threadIdx.x;
    const int w = tid >> 6, lane = tid & 63;
    const int m0 = blockIdx.x * 128, n0 = blockIdx.y * 128;
    const int arow = lane >> 2, achk = (lane & 3) * 8;
    const int frow = lane & 15, fchk = (lane >> 4) * 8;
    const int wr = (w >> 1) * 64, wc = (w & 1) * 64;

    f32x4 acc[4][4] = {};

    for (int k0 = 0; k0 < K; k0 += 32) {
        __syncthreads();
#pragma unroll
        for (int c = 0; c < 2; ++c) {
            int R = c * 64 + w * 16;
            load_lds16(A + (size_t)(m0 + R + arow) * lda + k0 + achk, sA + R * 32);
            load_lds16(Wt + (size_t)(n0 + R + arow) * K + k0 + achk, sB + R * 32);
        }
        __syncthreads();
        f16x8 af[4], bf[4];
#pragma unroll
        for (int i = 0; i < 4; ++i)
            af[i] = *(const f16x8*)&sA[(wr + i * 16 + frow) * 32 + fchk];
#pragma unroll
        for (int j = 0; j < 4; ++j)
            bf[j] = *(const f16x8*)&sB[(wc + j * 16 + frow) * 32 + fchk];
#pragma unroll
        for (int i = 0; i < 4; ++i)
#pragma unroll
            for (int j = 0; j < 4; ++j)
                acc[i][j] = __builtin_amdgcn_mfma_f32_16x16x32_f16(af[i], bf[j], acc[i][j], 0, 0, 0);
    }

    // epilogue: lane owns unit u, acc[i][j][r] = gate j of row m
    const int u = blockIdx.y * 32 + (w & 1) * 16 + (lane & 15);
    const float4 bb = *(const float4*)&bias4[u * 4];
    const int rbase = m0 + wr + (lane >> 4) * 4;
#pragma unroll
    for (int i = 0; i < 4; ++i) {
#pragma unroll
        for (int r = 0; r < 4; ++r) {
            int m = rbase + i * 16 + r;
            if (m < M) {
                float gi = sigmoidf_(acc[i][0][r] + bb.x);
                float gf = sigmoidf_(acc[i][1][r] + bb.y);
                float gg = tanhf2_(acc[i][2][r] + bb.z);
                float go = sigmoidf_(acc[i][3][r] + bb.w);
                float cold = c_state[(size_t)m * 256 + u];
                float cn = gf * cold + gi * gg;
                c_state[(size_t)m * 256 + u] = cn;
                f16 h = (f16)(go * tanhf2_(cn));
                hA[(size_t)m * ldhA + offhA + u] = h;
                if (hB) hB[(size_t)m * ldhB + offhB + u] = h;
            }
        }
    }
    // layer0 blocks (y==0) stage x_{t+1} into A0next cols 0..15
    if (xsrc && blockIdx.y == 0) {
        int row = tid >> 1, fb = (tid & 1) * 8;
        int m = m0 + row;
        if (m < M) {
            const float* xp = xsrc + (size_t)m * 960 + tnext * 16 + fb;
            f16* dp = hB + (size_t)m * ldhB + fb;
#pragma unroll
            for (int q = 0; q < 8; ++q) dp[q] = (f16)xp[q];
        }
    }
}

// solo (single-layer) LSTM step
__global__ __launch_bounds__(256) void lstm_mfma_kernel(
    const f16* __restrict__ A, int lda, int K,
    const f16* __restrict__ Wt, const float* __restrict__ bias4,
    float* __restrict__ c_state,
    f16* __restrict__ hA, int ldhA, int offhA,
    f16* __restrict__ hB, int ldhB, int offhB,
    const float* __restrict__ xsrc, int tnext, int M)
{
    __shared__ __align__(16) f16 sA[128 * 32];
    __shared__ __align__(16) f16 sB[128 * 32];
    lstm_step_core(sA, sB, A, lda, K, Wt, bias4, c_state,
                   hA, ldhA, offhA, hB, ldhB, offhB, xsrc, tnext, M);
}

// merged: z=0 -> layer1(t), z=1 -> layer0(t+1)  (mutually independent)
__global__ __launch_bounds__(256) void lstm_dual_kernel(
    const f16* __restrict__ A1, const f16* __restrict__ W1t,
    const float* __restrict__ b41, float* __restrict__ c1,
    f16* __restrict__ h1A, int ldh1A, int offh1A,
    const f16* __restrict__ A0, const f16* __restrict__ W0t,
    const float* __restrict__ b40, float* __restrict__ c0,
    f16* __restrict__ h0A, int ldh0A, int offh0A,
    f16* __restrict__ h0B, int ldh0B, int offh0B,
    const float* __restrict__ xsrc, int tnext, int M)
{
    __shared__ __align__(16) f16 sA[128 * 32];
    __shared__ __align__(16) f16 sB[128 * 32];
    if (blockIdx.z == 0)
        lstm_step_core(sA, sB, A1, 512, 512, W1t, b41, c1,
                       h1A, ldh1A, offh1A, nullptr, 0, 0, nullptr, 0, M);
    else
        lstm_step_core(sA, sB, A0, 288, 288, W0t, b40, c0,
                       h0A, ldh0A, offh0A, h0B, ldh0B, offh0B, xsrc, tnext, M);
}

// ---------------------------------------------------------------------------
// Generic f16 MFMA GEMM: C = act(A[M,lda(K cols)] @ Bt[N,K]^T + bias)
// ---------------------------------------------------------------------------
__global__ __launch_bounds__(256) void gemm16_kernel(
    const f16* __restrict__ A, int lda,
    const f16* __restrict__ Bt, int K,
    const float* __restrict__ bias,
    f16* __restrict__ C16, float* __restrict__ C32, int ldc,
    int act, int M)
{
    __shared__ __align__(16) f16 sA[128 * 32];
    __shared__ __align__(16) f16 sB[128 * 32];
    const int tid = threadIdx.x;
    const int w = tid >> 6, lane = tid & 63;
    const int m0 = blockIdx.x * 128, n0 = blockIdx.y * 128;
    const int arow = lane >> 2, achk = (lane & 3) * 8;
    const int frow = lane & 15, fchk = (lane >> 4) * 8;
    const int wr = (w >> 1) * 64, wcn = (w & 1) * 64;

    f32x4 acc[4][4] = {};

    for (int k0 = 0; k0 < K; k0 += 32) {
        __syncthreads();
#pragma unroll
        for (int c = 0; c < 2; ++c) {
            int R = c * 64 + w * 16;
            load_lds16(A + (size_t)(m0 + R + arow) * lda + k0 + achk, sA + R * 32);
            load_lds16(Bt + (size_t)(n0 + R + arow) * K + k0 + achk, sB + R * 32);
        }
        __syncthreads();
        f16x8 af[4], bf[4];
#pragma unroll
        for (int i = 0; i < 4; ++i)
            af[i] = *(const f16x8*)&sA[(wr + i * 16 + frow) * 32 + fchk];
#pragma unroll
        for (int j = 0; j < 4; ++j)
            bf[j] = *(const f16x8*)&sB[(wcn + j * 16 + frow) * 32 + fchk];
#pragma unroll
        for (int i = 0; i < 4; ++i)
#pragma unroll
            for (int j = 0; j < 4; ++j)
                acc[i][j] = __builtin_amdgcn_mfma_f32_16x16x32_f16(af[i], bf[j], acc[i][j], 0, 0, 0);
    }

    const int rbase = m0 + wr + (lane >> 4) * 4;
#pragma unroll
    for (int i = 0; i < 4; ++i) {
#pragma unroll
        for (int r = 0; r < 4; ++r) {
            int m = rbase + i * 16 + r;
            if (m >= M) continue;
#pragma unroll
            for (int j = 0; j < 4; ++j) {
                int n = n0 + wcn + j * 16 + (lane & 15);
                float v = acc[i][j][r] + bias[n];
                if (act == 1) v = fmaxf(v, 0.f);
                if (C16) C16[(size_t)m * ldc + n] = (f16)v;
                else     C32[(size_t)m * ldc + n] = v;
            }
        }
    }
}

// dual-B variant: y<4 -> (Btl,biasl,Cl), y>=4 -> (Btr,biasr,Cr). fp16 out.
__global__ __launch_bounds__(256) void gemm16_dual_kernel(
    const f16* __restrict__ A, int lda,
    const f16* __restrict__ Btl, const f16* __restrict__ Btr, int K,
    const float* __restrict__ biasl, const float* __restrict__ biasr,
    f16* __restrict__ Cl, f16* __restrict__ Cr, int ldc, int M)
{
    __shared__ __align__(16) f16 sA[128 * 32];
    __shared__ __align__(16) f16 sB[128 * 32];
    const int side = blockIdx.y >> 2;
    const f16* Bt = side ? Btr : Btl;
    const float* bias = side ? biasr : biasl;
    f16* C16 = side ? Cr : Cl;
    const int tid = threadIdx.x;
    const int w = tid >> 6, lane = tid & 63;
    const int m0 = blockIdx.x * 128, n0 = (blockIdx.y & 3) * 128;
    const int arow = lane >> 2, achk = (lane & 3) * 8;
    const int frow = lane & 15, fchk = (lane >> 4) * 8;
    const int wr = (w >> 1) * 64, wcn = (w & 1) * 64;

    f32x4 acc[4][4] = {};

    for (int k0 = 0; k0 < K; k0 += 32) {
        __syncthreads();
#pragma unroll
        for (int c = 0; c < 2; ++c) {
            int R = c * 64 + w * 16;
            load_lds16(A + (size_t)(m0 + R + arow) * lda + k0 + achk, sA + R * 32);
            load_lds16(Bt + (size_t)(n0 + R + arow) * K + k0 + achk, sB + R * 32);
        }
        __syncthreads();
        f16x8 af[4], bf[4];
#pragma unroll
        for (int i = 0; i < 4; ++i)
            af[i] = *(const f16x8*)&sA[(wr + i * 16 + frow) * 32 + fchk];
#pragma unroll
        for (int j = 0; j < 4; ++j)
            bf[j] = *(const f16x8*)&sB[(wcn + j * 16 + frow) * 32 + fchk];
#pragma unroll
        for (int i = 0; i < 4; ++i)
#pragma unroll
            for (int j = 0; j < 4; ++j)
                acc[i][j] = __builtin_amdgcn_mfma_f32_16x16x32_f16(af[i], bf[j], acc[i][j], 0, 0, 0);
    }

    const int rbase = m0 + wr + (lane >> 4) * 4;
#pragma unroll
    for (int i = 0; i < 4; ++i) {
#pragma unroll
        for (int r = 0; r < 4; ++r) {
            int m = rbase + i * 16 + r;
            if (m >= M) continue;
#pragma unroll
            for (int j = 0; j < 4; ++j) {
                int n = n0 + wcn + j * 16 + (lane & 15);
                float v = acc[i][j][r] + bias[n];
                C16[(size_t)m * ldc + n] = (f16)v;
            }
        }
    }
}

// ---------------------------------------------------------------------------
// Edge preprocessing
// ---------------------------------------------------------------------------
__global__ void mean_sum_kernel(const float* __restrict__ a, int n, float* __restrict__ out) {
    __shared__ float s[256];
    float loc = 0.f;
    for (int i = blockIdx.x * 256 + threadIdx.x; i < n; i += gridDim.x * 256) loc += a[i];
    s[threadIdx.x] = loc;
    __syncthreads();
    for (int off = 128; off; off >>= 1) {
        if (threadIdx.x < off) s[threadIdx.x] += s[threadIdx.x + off];
        __syncthreads();
    }
    if (threadIdx.x == 0) atomicAdd(out, s[0]);
}

__global__ void hist_kernel(const int* __restrict__ ei, int Ne, int Nn,
                            int* __restrict__ counts) {
    int e = blockIdx.x * 256 + threadIdx.x;
    if (e >= Ne + Nn) return;
    int d = (e < Ne) ? ei[Ne + e] : (e - Ne);
    atomicAdd(&counts[d], 1);
}

__global__ void scan_kernel(const int* __restrict__ counts, int* __restrict__ offsets, int n) {
    __shared__ int s[256];
    int tid = threadIdx.x;
    int chunk = (n + 255) / 256;
    int b = tid * chunk;
    int loc = 0;
    for (int j = 0; j < chunk; ++j) { int i = b + j; if (i < n) loc += counts[i]; }
    s[tid] = loc;
    __syncthreads();
    for (int off = 1; off < 256; off <<= 1) {
        int v = (tid >= off) ? s[tid - off] : 0;
        __syncthreads();
        s[tid] += v;
        __syncthreads();
    }
    int run = (tid == 0) ? 0 : s[tid - 1];
    for (int j = 0; j < chunk; ++j) {
        int i = b + j;
        if (i < n) { offsets[i] = run; run += counts[i]; }
    }
    if (tid == 255) offsets[n] = run;
}

__global__ void scatter_kernel(const int* __restrict__ ei, const float* __restrict__ ea,
                               const float* __restrict__ sump, float inv_ne, int Ne, int Nn,
                               int* __restrict__ cursor, int* __restrict__ src_sorted,
                               float* __restrict__ ea_sorted) {
    int e = blockIdx.x * 256 + threadIdx.x;
    if (e >= Ne + Nn) return;
    int s, d; float a;
    if (e < Ne) { s = ei[e]; d = ei[Ne + e]; a = ea[e]; }
    else        { s = e - Ne; d = s; a = sump[0] * inv_ne; }
    int pos = atomicAdd(&cursor[d], 1);
    src_sorted[pos] = s;
    ea_sorted[pos] = a;
}

// ---------------------------------------------------------------------------
// GATv2 attention + aggregation (fp16 xl/xr), one block per dst node.
// ---------------------------------------------------------------------------
__global__ __launch_bounds__(256) void gat_aggregate_kernel(
    const f16* __restrict__ xl, const f16* __restrict__ xr,
    const float* __restrict__ we, const float* __restrict__ att,
    const float* __restrict__ bias,
    const int* __restrict__ offsets, const int* __restrict__ src_sorted,
    const float* __restrict__ ea_sorted,
    float* __restrict__ logit_buf, f16* __restrict__ out, int ldo, int N)
{
    __shared__ float s_xr[512], s_we[512], s_att[512];
    __shared__ float s_wmax[32], s_mx[8], s_den[8], s_rden[8];
    __shared__ float s_alpha[256];
    __shared__ int s_src[32];
    const int i = blockIdx.x;
    const int tid = threadIdx.x;
    s_xr[tid]       = (float)xr[(size_t)i * 512 + tid];
    s_xr[tid + 256] = (float)xr[(size_t)i * 512 + tid + 256];
    s_we[tid] = we[tid]; s_we[tid + 256] = we[tid + 256];
    s_att[tid] = att[tid]; s_att[tid + 256] = att[tid + 256];
    if (tid < 8) s_den[tid] = 0.f;
    __syncthreads();

    const int beg = offsets[i], end = offsets[i + 1];
    const int w = tid >> 6, lane = tid & 63;

    float wm[4] = {-1e30f, -1e30f, -1e30f, -1e30f};
    for (int e = beg + w; e < end; e += 4) {
        int s = src_sorted[e];
        float a = ea_sorted[e];
        float part[4];
#pragma unroll
        for (int cc = 0; cc < 4; ++cc) {
            int col = cc * 128 + lane * 2;
            f16x2 xv = *(const f16x2*)&xl[(size_t)s * 512 + col];
            float v0 = (float)xv.x + s_xr[col]     + a * s_we[col];
            float v1 = (float)xv.y + s_xr[col + 1] + a * s_we[col + 1];
            v0 = (v0 > 0.f) ? v0 : 0.2f * v0;
            v1 = (v1 > 0.f) ? v1 : 0.2f * v1;
            part[cc] = v0 * s_att[col] + v1 * s_att[col + 1];
        }
#pragma unroll
        for (int off = 16; off; off >>= 1)
#pragma unroll
            for (int cc = 0; cc < 4; ++cc) part[cc] += __shfl_xor(part[cc], off);
        if ((lane & 31) == 0) {
            int hb = lane >> 5;
#pragma unroll
            for (int cc = 0; cc < 4; ++cc) {
                logit_buf[(size_t)e * 8 + 2 * cc + hb] = part[cc];
                wm[cc] = fmaxf(wm[cc], part[cc]);
            }
        }
    }
    if ((lane & 31) == 0) {
        int hb = lane >> 5;
#pragma unroll
        for (int cc = 0; cc < 4; ++cc) s_wmax[w * 8 + 2 * cc + hb] = wm[cc];
    }
    __syncthreads();
    if (tid < 8) {
        float m = fmaxf(fmaxf(s_wmax[tid], s_wmax[8 + tid]),
                        fmaxf(s_wmax[16 + tid], s_wmax[24 + tid]));
        s_mx[tid] = m;
    }
    __syncthreads();

    for (int e = beg + tid; e < end; e += 256) {
#pragma unroll
        for (int h = 0; h < 8; ++h) {
            float ex = __expf(logit_buf[(size_t)e * 8 + h] - s_mx[h]);
            logit_buf[(size_t)e * 8 + h] = ex;
            atomicAdd(&s_den[h], ex);
        }
    }
    __syncthreads();
    if (tid < 8) s_rden[tid] = 1.f / s_den[tid];
    __syncthreads();

    float acc0 = 0.f, acc1 = 0.f;
    const int c2 = tid * 2, hh = tid >> 5;
    for (int chunk = beg; chunk < end; chunk += 32) {
        int cnt = min(32, end - chunk);
        if (tid < cnt) s_src[tid] = src_sorted[chunk + tid];
        int eo = tid >> 3, hq = tid & 7;
        if (eo < cnt) s_alpha[tid] = logit_buf[(size_t)(chunk + eo) * 8 + hq] * s_rden[hq];
        __syncthreads();
        for (int j = 0; j < cnt; ++j) {
            int s = s_src[j];
            f16x2 xv = *(const f16x2*)&xl[(size_t)s * 512 + c2];
            float al = s_alpha[j * 8 + hh];
            acc0 += al * (float)xv.x;
            acc1 += al * (float)xv.y;
        }
        __syncthreads();
    }
    float v0 = acc0 + bias[c2];
    float v1 = acc1 + bias[c2 + 1];
    v0 = (v0 > 0.f) ? v0 : __expf(v0) - 1.f;
    v1 = (v1 > 0.f) ? v1 : __expf(v1) - 1.f;
    f16x2 ov; ov.x = (f16)v0; ov.y = (f16)v1;
    *(f16x2*)&out[(size_t)i * ldo + c2] = ov;
}

// fc2: out[n] = H[n,:512] . w + b (fp32)
__global__ void fc2_kernel(const float* __restrict__ H, const float* __restrict__ w,
                           const float* __restrict__ b, float* __restrict__ out, int N) {
    int wv = threadIdx.x >> 6, lane = threadIdx.x & 63;
    int node = blockIdx.x * 4 + wv;
    if (node >= N) return;
    float s = 0.f;
#pragma unroll
    for (int j = 0; j < 8; ++j)
        s += H[(size_t)node * 512 + j * 64 + lane] * w[j * 64 + lane];
#pragma unroll
    for (int off = 32; off; off >>= 1) s += __shfl_xor(s, off, 64);
    if (lane == 0) out[node] = s + b[0];
}

// ---------------------------------------------------------------------------
extern "C" void kernel_launch(void* const* d_in, const int* in_sizes, int n_in,
                              void* d_out, int out_size, void* d_ws, size_t ws_size,
                              hipStream_t stream) {
    const float* x_seq     = (const float*)d_in[0];
    const int*   edge_index= (const int*)d_in[1];
    const float* edge_attr = (const float*)d_in[2];
    const float* w_ih0 = (const float*)d_in[3];
    const float* w_hh0 = (const float*)d_in[4];
    const float* b_ih0 = (const float*)d_in[5];
    const float* b_hh0 = (const float*)d_in[6];
    const float* w_ih1 = (const float*)d_in[7];
    const float* w_hh1 = (const float*)d_in[8];
    const float* b_ih1 = (const float*)d_in[9];
    const float* b_hh1 = (const float*)d_in[10];
    const float* g0_wl = (const float*)d_in[11];
    const float* g0_bl = (const float*)d_in[12];
    const float* g0_wr = (const float*)d_in[13];
    const float* g0_br = (const float*)d_in[14];
    const float* g0_we = (const float*)d_in[15];
    const float* g0_att= (const float*)d_in[16];
    const float* g0_bias=(const float*)d_in[17];
    const float* g1_wl = (const float*)d_in[18];
    const float* g1_bl = (const float*)d_in[19];
    const float* g1_wr = (const float*)d_in[20];
    const float* g1_br = (const float*)d_in[21];
    const float* g1_we = (const float*)d_in[22];
    const float* g1_att= (const float*)d_in[23];
    const float* g1_bias=(const float*)d_in[24];
    const float* fc1_w = (const float*)d_in[25];
    const float* fc1_b = (const float*)d_in[26];
    const float* fc2_w = (const float*)d_in[27];
    const float* fc2_b = (const float*)d_in[28];
    float* out = (float*)d_out;

    const int Nn = in_sizes[0] / (60 * 16);   // 10000
    const int Ne = in_sizes[1] / 2;           // 320000
    const int Etot = Ne + Nn;
    const int MT = (Nn + 127) / 128;          // 79
    const int Mpad = MT * 128;                // 10112

    size_t off = 0;
    auto alloc = [&](size_t bytes) -> void* {
        void* r = (char*)d_ws + off;
        off += (bytes + 255) & ~(size_t)255;
        return r;
    };
    f16* W0t   = (f16*)alloc((size_t)1024 * 288 * 2);
    f16* W1t   = (f16*)alloc((size_t)1024 * 512 * 2);
    float* b40 = (float*)alloc(1024 * 4);
    float* b41 = (float*)alloc(1024 * 4);
    f16* Wg0l  = (f16*)alloc((size_t)512 * 256 * 2);
    f16* Wg0r  = (f16*)alloc((size_t)512 * 256 * 2);
    f16* Wg1l  = (f16*)alloc((size_t)512 * 512 * 2);
    f16* Wg1r  = (f16*)alloc((size_t)512 * 512 * 2);
    f16* Wfc1  = (f16*)alloc((size_t)512 * 768 * 2);
    f16* A0b[2]; A0b[0] = (f16*)alloc((size_t)Mpad * 288 * 2);
                 A0b[1] = (f16*)alloc((size_t)Mpad * 288 * 2);
    f16* A1b[2]; A1b[0] = (f16*)alloc((size_t)Mpad * 512 * 2);
                 A1b[1] = (f16*)alloc((size_t)Mpad * 512 * 2);
    float* c0  = (float*)alloc((size_t)Mpad * 256 * 4);
    float* c1  = (float*)alloc((size_t)Mpad * 256 * 4);
    f16* fused = (f16*)alloc((size_t)Mpad * 768 * 2);
    f16* xlbuf = (f16*)alloc((size_t)Mpad * 512 * 2);
    f16* xrbuf = (f16*)alloc((size_t)Mpad * 512 * 2);
    f16* gbuf  = (f16*)alloc((size_t)Mpad * 512 * 2);
    float* hfc1= (float*)alloc((size_t)Mpad * 512 * 4);
    float* logit_buf = (float*)alloc((size_t)Etot * 8 * 4);
    int* counts  = (int*)alloc((size_t)Nn * 4);
    int* offsets = (int*)alloc((size_t)(Nn + 1) * 4);
    int* cursor  = (int*)alloc((size_t)Nn * 4);
    int* src_sorted = (int*)alloc((size_t)Etot * 4);
    float* ea_sorted = (float*)alloc((size_t)Etot * 4);
    float* meanp = (float*)alloc(256);

    // ---- weight / state prep ----
    prep_w0_kernel<<<dim3((1024 * 288 + 255) / 256), 256, 0, stream>>>(w_ih0, w_hh0, W0t);
    prep_w1_kernel<<<dim3((1024 * 512 + 255) / 256), 256, 0, stream>>>(w_ih1, w_hh1, W1t);
    prep_bias4_kernel<<<dim3(4), 256, 0, stream>>>(b_ih0, b_hh0, b40);
    prep_bias4_kernel<<<dim3(4), 256, 0, stream>>>(b_ih1, b_hh1, b41);
    prep_wt_kernel<<<dim3((256 * 512 + 255) / 256), 256, 0, stream>>>(g0_wl, Wg0l, 256, 512);
    prep_wt_kernel<<<dim3((256 * 512 + 255) / 256), 256, 0, stream>>>(g0_wr, Wg0r, 256, 512);
    prep_wt_kernel<<<dim3((512 * 512 + 255) / 256), 256, 0, stream>>>(g1_wl, Wg1l, 512, 512);
    prep_wt_kernel<<<dim3((512 * 512 + 255) / 256), 256, 0, stream>>>(g1_wr, Wg1r, 512, 512);
    prep_wt_kernel<<<dim3((768 * 512 + 255) / 256), 256, 0, stream>>>(fc1_w, Wfc1, 768, 512);
    hipMemsetAsync(A0b[0], 0, (size_t)Mpad * 288 * 2, stream);
    hipMemsetAsync(A1b[0], 0, (size_t)Mpad * 512 * 2, stream);
    hipMemsetAsync(c0, 0, (size_t)Mpad * 256 * 4, stream);
    hipMemsetAsync(c1, 0, (size_t)Mpad * 256 * 4, stream);
    prep_x0_kernel<<<dim3((Nn * 16 + 255) / 256), 256, 0, stream>>>(x_seq, A0b[0], Nn);

    // ---- edge prep (CSR by dst) ----
    hipMemsetAsync(meanp, 0, 4, stream);
    hipMemsetAsync(counts, 0, (size_t)Nn * 4, stream);
    mean_sum_kernel<<<dim3(256), 256, 0, stream>>>(edge_attr, Ne, meanp);
    hist_kernel<<<dim3((Etot + 255) / 256), 256, 0, stream>>>(edge_index, Ne, Nn, counts);
    scan_kernel<<<dim3(1), 256, 0, stream>>>(counts, offsets, Nn);
    hipMemcpyAsync(cursor, offsets, (size_t)Nn * 4, hipMemcpyDeviceToDevice, stream);
    scatter_kernel<<<dim3((Etot + 255) / 256), 256, 0, stream>>>(
        edge_index, edge_attr, meanp, 1.0f / (float)Ne, Ne, Nn, cursor, src_sorted, ea_sorted);

    // ---- 2-layer LSTM, 60 steps; L1(t) and L0(t+1) co-scheduled ----
    dim3 lgrid(MT, 8);
    dim3 dgrid(MT, 8, 2);
    // L0(0)
    lstm_mfma_kernel<<<lgrid, 256, 0, stream>>>(
        A0b[0], 288, 288, W0t, b40, c0,
        A1b[0], 512, 0,
        A0b[1], 288, 16,
        x_seq, 1, Nn);
    // merged L1(k) + L0(k+1), k = 0..58
    for (int k = 0; k < 59; ++k) {
        lstm_dual_kernel<<<dgrid, 256, 0, stream>>>(
            A1b[k & 1], W1t, b41, c1,
            A1b[(k + 1) & 1], 512, 256,
            A0b[(k + 1) & 1], W0t, b40, c0,
            A1b[(k + 1) & 1], 512, 0,
            A0b[k & 1], 288, 16,
            (k + 1 < 59) ? x_seq : nullptr, k + 2, Nn);
    }
    // L1(59): write h1_59 (node) directly into fused cols 0..255
    lstm_mfma_kernel<<<lgrid, 256, 0, stream>>>(
        A1b[1], 512, 512, W1t, b41, c1,
        fused, 768, 0,
        nullptr, 0, 0,
        nullptr, 0, Nn);

    // ---- GAT layer 1 (xl/xr in one launch) ----
    gemm16_dual_kernel<<<dim3(MT, 8), 256, 0, stream>>>(
        fused, 768, Wg0l, Wg0r, 256, g0_bl, g0_br, xlbuf, xrbuf, 512, Nn);
    gat_aggregate_kernel<<<dim3(Nn), 256, 0, stream>>>(
        xlbuf, xrbuf, g0_we, g0_att, g0_bias, offsets, src_sorted, ea_sorted,
        logit_buf, gbuf, 512, Nn);

    // ---- GAT layer 2 (output into fused cols 256..767) ----
    gemm16_dual_kernel<<<dim3(MT, 8), 256, 0, stream>>>(
        gbuf, 512, Wg1l, Wg1r, 512, g1_bl, g1_br, xlbuf, xrbuf, 512, Nn);
    gat_aggregate_kernel<<<dim3(Nn), 256, 0, stream>>>(
        xlbuf, xrbuf, g1_we, g1_att, g1_bias, offsets, src_sorted, ea_sorted,
        logit_buf, fused + 256, 768, Nn);

    // ---- fusion MLP ----
    gemm16_kernel<<<dim3(MT, 4), 256, 0, stream>>>(
        fused, 768, Wfc1, 768, fc1_b, nullptr, hfc1, 512, 1, Nn);
    fc2_kernel<<<dim3((Nn + 3) / 4), 256, 0, stream>>>(hfc1, fc2_w, fc2_b, out, Nn);
}